// Round 1
// baseline (7791.364 us; speedup 1.0000x reference)
//
#include <hip/hip_runtime.h>
#include <hip/hip_bf16.h>
#include <cstdint>
#include <cstddef>

#define E_N 600000
#define NND 50000
#define L 128

typedef unsigned short u16;
typedef unsigned int u32;

static __device__ __forceinline__ u16 f2bf(float f) {
  union { float f; u32 u; } c; c.f = f;
  return (u16)((c.u + 0x7fffu + ((c.u >> 16) & 1u)) >> 16);
}
static __device__ __forceinline__ float bf2f(u32 h) {
  union { u32 u; float f; } c; c.u = h << 16; return c.f;
}
static __device__ __forceinline__ void atomAddF(float* p, float v) {
#if defined(__HIP_DEVICE_COMPILE__)
  unsafeAtomicAdd(p, v);
#else
  atomicAdd(p, v);
#endif
}

// ---------------- edge layer 1: h1 = concat(x[dst],x[src],ea) @ W1 + b1 ; BN stats ----------------
__global__ __launch_bounds__(256) void k_edge_l1(
    const float* __restrict__ x, const float* __restrict__ ea,
    const int* __restrict__ srcI, const int* __restrict__ dstI,
    const float* __restrict__ W, const float* __restrict__ b,
    u16* __restrict__ h1, float* __restrict__ gS)
{
  __shared__ float As[32][64];
  __shared__ float Ws[32][128];
  __shared__ int sIdx[2][64];
  __shared__ float red[256];
  const int tid = threadIdx.x;
  const int bid = blockIdx.x;
  const int row0 = bid * 64;
  if (tid < 64) sIdx[0][tid] = dstI[row0 + tid];
  else if (tid < 128) sIdx[1][tid - 64] = srcI[row0 + tid - 64];
  red[tid] = 0.f;
  __syncthreads();

  const int tx = tid & 31, ty = tid >> 5;
  const int lr = tid & 63, lq = tid >> 6;
  float acc[8][4] = {};

  for (int kt = 0; kt < 384; kt += 32) {
    #pragma unroll
    for (int h = 0; h < 2; ++h) {
      const int kq = lq + h * 4;
      const int kk = kt + kq * 4;
      const float* sp; int co;
      if (kk < 128)      { sp = x + (size_t)sIdx[0][lr] * L; co = kk; }
      else if (kk < 256) { sp = x + (size_t)sIdx[1][lr] * L; co = kk - 128; }
      else               { sp = ea + (size_t)(row0 + lr) * L; co = kk - 256; }
      const float4 v = *(const float4*)(sp + co);
      As[kq*4+0][lr] = v.x; As[kq*4+1][lr] = v.y;
      As[kq*4+2][lr] = v.z; As[kq*4+3][lr] = v.w;
    }
    #pragma unroll
    for (int i = 0; i < 4; ++i) {
      const int slot = tid + i * 256;
      const int kk = slot >> 5, cq = slot & 31;
      *(float4*)&Ws[kk][cq*4] = *(const float4*)(W + (size_t)(kt + kk) * L + cq * 4);
    }
    __syncthreads();
    #pragma unroll
    for (int k = 0; k < 32; ++k) {
      float av[8], wv[4];
      *(float4*)&av[0] = *(const float4*)&As[k][ty*8];
      *(float4*)&av[4] = *(const float4*)&As[k][ty*8+4];
      *(float4*)&wv[0] = *(const float4*)&Ws[k][tx*4];
      #pragma unroll
      for (int r = 0; r < 8; ++r)
        #pragma unroll
        for (int j = 0; j < 4; ++j)
          acc[r][j] = fmaf(av[r], wv[j], acc[r][j]);
    }
    __syncthreads();
  }

  float bb[4];
  #pragma unroll
  for (int j = 0; j < 4; ++j) bb[j] = b[tx*4 + j];
  float s1[4] = {}, s2[4] = {};
  #pragma unroll
  for (int r = 0; r < 8; ++r) {
    const int row = row0 + ty*8 + r;
    float o[4];
    #pragma unroll
    for (int j = 0; j < 4; ++j) { o[j] = acc[r][j] + bb[j]; s1[j] += o[j]; s2[j] += o[j]*o[j]; }
    ushort4 st; st.x = f2bf(o[0]); st.y = f2bf(o[1]); st.z = f2bf(o[2]); st.w = f2bf(o[3]);
    *(ushort4*)(h1 + (size_t)row * L + tx*4) = st;
  }
  #pragma unroll
  for (int j = 0; j < 4; ++j) {
    atomAddF(&red[tx*4 + j], s1[j]);
    atomAddF(&red[128 + tx*4 + j], s2[j]);
  }
  __syncthreads();
  const int slot = (bid & 63) * L;
  if (tid < 128) atomAddF(&gS[slot + tid], red[tid]);
  else atomAddF(&gS[64*L + slot + (tid - 128)], red[tid]);
}

// ---------------- BN finalize: scale/shift per column ----------------
__global__ void k_bnfin(const float* __restrict__ gS, const float* __restrict__ g,
                        const float* __restrict__ be, float invM, float* __restrict__ ss)
{
  const int c = threadIdx.x;
  float s1 = 0.f, s2 = 0.f;
  for (int j = 0; j < 64; ++j) { s1 += gS[j*L + c]; s2 += gS[64*L + j*L + c]; }
  const float mean = s1 * invM;
  const float var = s2 * invM - mean * mean;
  const float sc = g[c] * rsqrtf(var + 1e-5f);
  ss[c] = sc;
  ss[L + c] = be[c] - mean * sc;
}

// ---------------- edge layer 2: ea += relu(relu(BN(h1)) @ W2 + b2) ; scatter to agg ----------------
__global__ __launch_bounds__(256) void k_edge_l2(
    const u16* __restrict__ h1, const float* __restrict__ ss,
    const float* __restrict__ W, const float* __restrict__ b,
    float* __restrict__ ea, const int* __restrict__ dstI,
    float* __restrict__ agg)
{
  __shared__ float As[32][64];
  __shared__ float Ws[32][128];
  __shared__ float sc[L], sh[L];
  __shared__ int sDst[64];
  const int tid = threadIdx.x, bid = blockIdx.x, row0 = bid * 64;
  if (tid < 128) sc[tid] = ss[tid]; else sh[tid - 128] = ss[tid];
  if (tid < 64) sDst[tid] = dstI[row0 + tid];
  __syncthreads();

  const int tx = tid & 31, ty = tid >> 5;
  const int lr = tid & 63, lo = tid >> 6;
  float acc[8][4] = {};

  for (int kt = 0; kt < 128; kt += 32) {
    {
      const uint4 raw = *(const uint4*)(h1 + (size_t)(row0 + lr) * L + kt + lo * 8);
      #pragma unroll
      for (int j = 0; j < 4; ++j) {
        const u32 u = ((const u32*)&raw)[j];
        const int kl = lo*8 + j*2;
        const int kg = kt + kl;
        As[kl][lr]   = fmaxf(bf2f(u & 0xffffu) * sc[kg]     + sh[kg],     0.f);
        As[kl+1][lr] = fmaxf(bf2f(u >> 16)     * sc[kg + 1] + sh[kg + 1], 0.f);
      }
    }
    #pragma unroll
    for (int i = 0; i < 4; ++i) {
      const int slot = tid + i * 256;
      const int kk = slot >> 5, cq = slot & 31;
      *(float4*)&Ws[kk][cq*4] = *(const float4*)(W + (size_t)(kt + kk) * L + cq * 4);
    }
    __syncthreads();
    #pragma unroll
    for (int k = 0; k < 32; ++k) {
      float av[8], wv[4];
      *(float4*)&av[0] = *(const float4*)&As[k][ty*8];
      *(float4*)&av[4] = *(const float4*)&As[k][ty*8+4];
      *(float4*)&wv[0] = *(const float4*)&Ws[k][tx*4];
      #pragma unroll
      for (int r = 0; r < 8; ++r)
        #pragma unroll
        for (int j = 0; j < 4; ++j)
          acc[r][j] = fmaf(av[r], wv[j], acc[r][j]);
    }
    __syncthreads();
  }

  float bb[4];
  #pragma unroll
  for (int j = 0; j < 4; ++j) bb[j] = b[tx*4 + j];
  #pragma unroll
  for (int r = 0; r < 8; ++r) {
    const int row = row0 + ty*8 + r;
    float4 prev = *(const float4*)(ea + (size_t)row * L + tx*4);
    float o0 = fmaxf(acc[r][0] + bb[0], 0.f) + prev.x;
    float o1 = fmaxf(acc[r][1] + bb[1], 0.f) + prev.y;
    float o2 = fmaxf(acc[r][2] + bb[2], 0.f) + prev.z;
    float o3 = fmaxf(acc[r][3] + bb[3], 0.f) + prev.w;
    float4 o; o.x = o0; o.y = o1; o.z = o2; o.w = o3;
    *(float4*)(ea + (size_t)row * L + tx*4) = o;
    float* ap = agg + (size_t)sDst[ty*8 + r] * L + tx*4;
    atomAddF(ap + 0, o0); atomAddF(ap + 1, o1);
    atomAddF(ap + 2, o2); atomAddF(ap + 3, o3);
  }
}

// ---------------- node layer 1: h1n = concat(x,agg) @ nW1 + nb1 ; BN stats ----------------
__global__ __launch_bounds__(256) void k_node_l1(
    const float* __restrict__ x, const float* __restrict__ agg,
    const float* __restrict__ W, const float* __restrict__ b,
    u16* __restrict__ h1, float* __restrict__ gS)
{
  __shared__ float As[32][64];
  __shared__ float Ws[32][128];
  __shared__ float red[256];
  const int tid = threadIdx.x, bid = blockIdx.x, row0 = bid * 64;
  red[tid] = 0.f;
  __syncthreads();

  const int tx = tid & 31, ty = tid >> 5;
  const int lr = tid & 63, lq = tid >> 6;
  const int rr = min(row0 + lr, NND - 1);
  float acc[8][4] = {};

  for (int kt = 0; kt < 256; kt += 32) {
    #pragma unroll
    for (int h = 0; h < 2; ++h) {
      const int kq = lq + h * 4;
      const int kk = kt + kq * 4;
      const float* sp; int co;
      if (kk < 128) { sp = x + (size_t)rr * L; co = kk; }
      else          { sp = agg + (size_t)rr * L; co = kk - 128; }
      const float4 v = *(const float4*)(sp + co);
      As[kq*4+0][lr] = v.x; As[kq*4+1][lr] = v.y;
      As[kq*4+2][lr] = v.z; As[kq*4+3][lr] = v.w;
    }
    #pragma unroll
    for (int i = 0; i < 4; ++i) {
      const int slot = tid + i * 256;
      const int kk = slot >> 5, cq = slot & 31;
      *(float4*)&Ws[kk][cq*4] = *(const float4*)(W + (size_t)(kt + kk) * L + cq * 4);
    }
    __syncthreads();
    #pragma unroll
    for (int k = 0; k < 32; ++k) {
      float av[8], wv[4];
      *(float4*)&av[0] = *(const float4*)&As[k][ty*8];
      *(float4*)&av[4] = *(const float4*)&As[k][ty*8+4];
      *(float4*)&wv[0] = *(const float4*)&Ws[k][tx*4];
      #pragma unroll
      for (int r = 0; r < 8; ++r)
        #pragma unroll
        for (int j = 0; j < 4; ++j)
          acc[r][j] = fmaf(av[r], wv[j], acc[r][j]);
    }
    __syncthreads();
  }

  float bb[4];
  #pragma unroll
  for (int j = 0; j < 4; ++j) bb[j] = b[tx*4 + j];
  float s1[4] = {}, s2[4] = {};
  #pragma unroll
  for (int r = 0; r < 8; ++r) {
    const int row = row0 + ty*8 + r;
    if (row < NND) {
      float o[4];
      #pragma unroll
      for (int j = 0; j < 4; ++j) { o[j] = acc[r][j] + bb[j]; s1[j] += o[j]; s2[j] += o[j]*o[j]; }
      ushort4 st; st.x = f2bf(o[0]); st.y = f2bf(o[1]); st.z = f2bf(o[2]); st.w = f2bf(o[3]);
      *(ushort4*)(h1 + (size_t)row * L + tx*4) = st;
    }
  }
  #pragma unroll
  for (int j = 0; j < 4; ++j) {
    atomAddF(&red[tx*4 + j], s1[j]);
    atomAddF(&red[128 + tx*4 + j], s2[j]);
  }
  __syncthreads();
  const int slot = (bid & 63) * L;
  if (tid < 128) atomAddF(&gS[slot + tid], red[tid]);
  else atomAddF(&gS[64*L + slot + (tid - 128)], red[tid]);
}

// ---------------- node layer 2: x += relu(relu(BN(h1n)) @ nW2 + nb2) ----------------
__global__ __launch_bounds__(256) void k_node_l2(
    const u16* __restrict__ h1, const float* __restrict__ ss,
    const float* __restrict__ W, const float* __restrict__ b,
    float* __restrict__ x)
{
  __shared__ float As[32][64];
  __shared__ float Ws[32][128];
  __shared__ float sc[L], sh[L];
  const int tid = threadIdx.x, bid = blockIdx.x, row0 = bid * 64;
  if (tid < 128) sc[tid] = ss[tid]; else sh[tid - 128] = ss[tid];
  __syncthreads();

  const int tx = tid & 31, ty = tid >> 5;
  const int lr = tid & 63, lo = tid >> 6;
  const int rr = min(row0 + lr, NND - 1);
  float acc[8][4] = {};

  for (int kt = 0; kt < 128; kt += 32) {
    {
      const uint4 raw = *(const uint4*)(h1 + (size_t)rr * L + kt + lo * 8);
      #pragma unroll
      for (int j = 0; j < 4; ++j) {
        const u32 u = ((const u32*)&raw)[j];
        const int kl = lo*8 + j*2;
        const int kg = kt + kl;
        As[kl][lr]   = fmaxf(bf2f(u & 0xffffu) * sc[kg]     + sh[kg],     0.f);
        As[kl+1][lr] = fmaxf(bf2f(u >> 16)     * sc[kg + 1] + sh[kg + 1], 0.f);
      }
    }
    #pragma unroll
    for (int i = 0; i < 4; ++i) {
      const int slot = tid + i * 256;
      const int kk = slot >> 5, cq = slot & 31;
      *(float4*)&Ws[kk][cq*4] = *(const float4*)(W + (size_t)(kt + kk) * L + cq * 4);
    }
    __syncthreads();
    #pragma unroll
    for (int k = 0; k < 32; ++k) {
      float av[8], wv[4];
      *(float4*)&av[0] = *(const float4*)&As[k][ty*8];
      *(float4*)&av[4] = *(const float4*)&As[k][ty*8+4];
      *(float4*)&wv[0] = *(const float4*)&Ws[k][tx*4];
      #pragma unroll
      for (int r = 0; r < 8; ++r)
        #pragma unroll
        for (int j = 0; j < 4; ++j)
          acc[r][j] = fmaf(av[r], wv[j], acc[r][j]);
    }
    __syncthreads();
  }

  float bb[4];
  #pragma unroll
  for (int j = 0; j < 4; ++j) bb[j] = b[tx*4 + j];
  #pragma unroll
  for (int r = 0; r < 8; ++r) {
    const int row = row0 + ty*8 + r;
    if (row < NND) {
      float4 prev = *(const float4*)(x + (size_t)row * L + tx*4);
      float4 o;
      o.x = fmaxf(acc[r][0] + bb[0], 0.f) + prev.x;
      o.y = fmaxf(acc[r][1] + bb[1], 0.f) + prev.y;
      o.z = fmaxf(acc[r][2] + bb[2], 0.f) + prev.z;
      o.w = fmaxf(acc[r][3] + bb[3], 0.f) + prev.w;
      *(float4*)(x + (size_t)row * L + tx*4) = o;
    }
  }
}

extern "C" void kernel_launch(void* const* d_in, const int* in_sizes, int n_in,
                              void* d_out, int out_size, void* d_ws, size_t ws_size,
                              hipStream_t stream) {
  (void)in_sizes; (void)n_in; (void)out_size;
  const float* in_x  = (const float*)d_in[0];
  const float* in_ea = (const float*)d_in[1];
  const int*   ei    = (const int*)d_in[2];
  const float* eW1 = (const float*)d_in[3];
  const float* eb1 = (const float*)d_in[4];
  const float* eg1 = (const float*)d_in[5];
  const float* ebe1= (const float*)d_in[6];
  const float* eW2 = (const float*)d_in[7];
  const float* eb2 = (const float*)d_in[8];
  const float* nW1 = (const float*)d_in[9];
  const float* nb1 = (const float*)d_in[10];
  const float* ng1 = (const float*)d_in[11];
  const float* nbe1= (const float*)d_in[12];
  const float* nW2 = (const float*)d_in[13];
  const float* nb2 = (const float*)d_in[14];

  float* x  = (float*)d_out;                    // [NND][L]
  float* ea = (float*)d_out + (size_t)NND * L;  // [E_N][L]

  char* w = (char*)d_ws;
  u16* h1e  = (u16*)w;   w += (size_t)E_N * L * sizeof(u16);
  u16* h1n  = (u16*)w;   w += (size_t)NND * L * sizeof(u16);
  float* agg = (float*)w; w += (size_t)NND * L * sizeof(float);
  float* gS  = (float*)w; w += (size_t)2 * 64 * L * sizeof(float);
  float* ss  = (float*)w; w += (size_t)2 * L * sizeof(float);
  (void)ws_size; // requires ~192 MB of workspace

  const int* srcI = ei;        // edge_index[0]
  const int* dstI = ei + E_N;  // edge_index[1]

  hipMemcpyAsync(x, in_x, (size_t)NND * L * sizeof(float), hipMemcpyDeviceToDevice, stream);
  hipMemcpyAsync(ea, in_ea, (size_t)E_N * L * sizeof(float), hipMemcpyDeviceToDevice, stream);

  const int egrid = E_N / 64;            // 9375
  const int ngrid = (NND + 63) / 64;     // 782

  for (int s = 0; s < 4; ++s) {
    hipMemsetAsync(gS, 0, (size_t)2 * 64 * L * sizeof(float), stream);
    k_edge_l1<<<egrid, 256, 0, stream>>>(x, ea, srcI, dstI,
        eW1 + (size_t)s * 384 * L, eb1 + (size_t)s * L, h1e, gS);
    k_bnfin<<<1, 128, 0, stream>>>(gS, eg1 + (size_t)s * L, ebe1 + (size_t)s * L,
        1.f / (float)E_N, ss);
    hipMemsetAsync(agg, 0, (size_t)NND * L * sizeof(float), stream);
    k_edge_l2<<<egrid, 256, 0, stream>>>(h1e, ss,
        eW2 + (size_t)s * L * L, eb2 + (size_t)s * L, ea, dstI, agg);
    hipMemsetAsync(gS, 0, (size_t)2 * 64 * L * sizeof(float), stream);
    k_node_l1<<<ngrid, 256, 0, stream>>>(x, agg,
        nW1 + (size_t)s * 256 * L, nb1 + (size_t)s * L, h1n, gS);
    k_bnfin<<<1, 128, 0, stream>>>(gS, ng1 + (size_t)s * L, nbe1 + (size_t)s * L,
        1.f / (float)NND, ss);
    k_node_l2<<<ngrid, 256, 0, stream>>>(h1n, ss,
        nW2 + (size_t)s * L * L, nb2 + (size_t)s * L, x);
  }
}

// Round 2
// 2590.611 us; speedup vs baseline: 3.0075x; 3.0075x over previous
//
#include <hip/hip_runtime.h>
#include <hip/hip_bf16.h>
#include <cstdint>
#include <cstddef>

#define E_N 600000
#define NND 50000
#define L 128

typedef unsigned short u16;
typedef unsigned int u32;
typedef __attribute__((ext_vector_type(8))) short bf16x8;
typedef __attribute__((ext_vector_type(4))) float f32x4;

static __device__ __forceinline__ u16 f2bf(float f) {
  union { float f; u32 u; } c; c.f = f;
  return (u16)((c.u + 0x7fffu + ((c.u >> 16) & 1u)) >> 16);
}
static __device__ __forceinline__ u32 pk2(float a, float b) {
  return (u32)f2bf(a) | ((u32)f2bf(b) << 16);
}
static __device__ __forceinline__ float bf2f(u32 h) {
  union { u32 u; float f; } c; c.u = h << 16; return c.f;
}
static __device__ __forceinline__ void atomAddF(float* p, float v) {
#if defined(__HIP_DEVICE_COMPILE__)
  unsafeAtomicAdd(p, v);
#else
  atomicAdd(p, v);
#endif
}

// ================= weight pre-transpose: W[4][K][128] -> Wt[4][128][K] bf16 =================
__global__ void k_wt(const float* __restrict__ W, u16* __restrict__ Wt, int K) {
  const int idx = blockIdx.x * 256 + threadIdx.x;
  const int total = 4 * K * 128;
  if (idx >= total) return;
  const int s = idx / (K * 128);
  const int rem = idx - s * K * 128;
  const int n = rem / K;
  const int k = rem - n * K;
  Wt[idx] = f2bf(W[(size_t)s * K * 128 + (size_t)k * 128 + n]);
}

// ================= CSR build =================
__global__ void k_hist(const int* __restrict__ dstI, int* __restrict__ cnt) {
  const int i = blockIdx.x * 256 + threadIdx.x;
  if (i < E_N) atomicAdd(&cnt[dstI[i]], 1);
}

__global__ __launch_bounds__(1024) void k_scan(const int* __restrict__ cnt, int* __restrict__ startA) {
  __shared__ int buf[1024];
  __shared__ int carry;
  const int tid = threadIdx.x;
  if (tid == 0) carry = 0;
  __syncthreads();
  for (int base = 0; base < NND; base += 1024) {
    int v = (base + tid < NND) ? cnt[base + tid] : 0;
    buf[tid] = v;
    __syncthreads();
    for (int off = 1; off < 1024; off <<= 1) {
      int t = (tid >= off) ? buf[tid - off] : 0;
      __syncthreads();
      buf[tid] += t;
      __syncthreads();
    }
    const int incl = buf[tid];
    const int c = carry;
    if (base + tid < NND) startA[base + tid] = c + incl - v;
    __syncthreads();
    if (tid == 1023) carry = c + incl;
    __syncthreads();
  }
  if (tid == 0) startA[NND] = carry;
}

__global__ void k_fill(const int* __restrict__ dstI, const int* __restrict__ startA,
                       int* __restrict__ cur, int* __restrict__ eids) {
  const int i = blockIdx.x * 256 + threadIdx.x;
  if (i < E_N) {
    const int d = dstI[i];
    const int pos = atomicAdd(&cur[d], 1);
    eids[startA[d] + pos] = i;
  }
}

// ================= aggregation: agg[n] = sum of ea rows of node n's in-edges =================
__global__ __launch_bounds__(256) void k_agg(const float* __restrict__ ea,
                                             const int* __restrict__ startA,
                                             const int* __restrict__ eids,
                                             float* __restrict__ agg) {
  const int node = blockIdx.x * 4 + (threadIdx.x >> 6);
  const int lane = threadIdx.x & 63;
  if (node >= NND) return;
  const int s = startA[node], e = startA[node + 1];
  float2 a0 = {0.f, 0.f}, a1 = {0.f, 0.f};
  int i = s;
  for (; i + 1 < e; i += 2) {
    const float2 v0 = *(const float2*)(ea + (size_t)eids[i] * L + lane * 2);
    const float2 v1 = *(const float2*)(ea + (size_t)eids[i + 1] * L + lane * 2);
    a0.x += v0.x; a0.y += v0.y; a1.x += v1.x; a1.y += v1.y;
  }
  if (i < e) {
    const float2 v = *(const float2*)(ea + (size_t)eids[i] * L + lane * 2);
    a0.x += v.x; a0.y += v.y;
  }
  float2 o; o.x = a0.x + a1.x; o.y = a0.y + a1.y;
  *(float2*)(agg + (size_t)node * L + lane * 2) = o;
}

// ================= BN finalize =================
__global__ void k_bnfin(const float* __restrict__ gS, const float* __restrict__ g,
                        const float* __restrict__ be, float invM, float* __restrict__ ss) {
  const int c = threadIdx.x;
  float s1 = 0.f, s2 = 0.f;
  for (int j = 0; j < 64; ++j) { s1 += gS[j * L + c]; s2 += gS[64 * L + j * L + c]; }
  const float mean = s1 * invM;
  const float var = s2 * invM - mean * mean;
  const float sc = g[c] * rsqrtf(var + 1e-5f);
  ss[c] = sc;
  ss[L + c] = be[c] - mean * sc;
}

// ================= edge layer 1 (MFMA): h1 = concat(x[dst],x[src],ea) @ W1 + b1 ; BN stats =================
__global__ __launch_bounds__(256) void k_edge_l1(
    const float* __restrict__ x, const float* __restrict__ ea,
    const int* __restrict__ srcI, const int* __restrict__ dstI,
    const u16* __restrict__ Wt, const float* __restrict__ b,
    u16* __restrict__ h1, float* __restrict__ gS)
{
  __shared__ u16 As[64 * 64];
  __shared__ u16 Bs[128 * 64];
  __shared__ float red[256];
  char* AsB = (char*)As; char* BsB = (char*)Bs;
  const int tid = threadIdx.x, bid = blockIdx.x, row0 = bid * 64;
  red[tid] = 0.f;
  const int ar = tid >> 2, as = tid & 3;
  const int dI = dstI[row0 + ar], sI = srcI[row0 + ar];
  const int lane = tid & 63, wid = tid >> 6;
  const int wr = wid >> 1, wc = wid & 1;
  const int l15 = lane & 15, lq = lane >> 4;
  f32x4 acc[2][4];
  #pragma unroll
  for (int m = 0; m < 2; ++m)
    #pragma unroll
    for (int n = 0; n < 4; ++n) acc[m][n] = (f32x4){0.f, 0.f, 0.f, 0.f};

  for (int kc = 0; kc < 6; ++kc) {
    const float* sp;
    if (kc < 2)      sp = x + (size_t)dI * L + kc * 64;
    else if (kc < 4) sp = x + (size_t)sI * L + (kc - 2) * 64;
    else             sp = ea + (size_t)(row0 + ar) * L + (kc - 4) * 64;
    const float4 f0 = *(const float4*)(sp + as * 16);
    const float4 f1 = *(const float4*)(sp + as * 16 + 4);
    const float4 f2 = *(const float4*)(sp + as * 16 + 8);
    const float4 f3 = *(const float4*)(sp + as * 16 + 12);
    uint4 p0, p1;
    p0.x = pk2(f0.x, f0.y); p0.y = pk2(f0.z, f0.w);
    p0.z = pk2(f1.x, f1.y); p0.w = pk2(f1.z, f1.w);
    p1.x = pk2(f2.x, f2.y); p1.y = pk2(f2.z, f2.w);
    p1.z = pk2(f3.x, f3.y); p1.w = pk2(f3.z, f3.w);
    const int abyte = ar * 128 + as * 32, asw = (ar & 7) << 4;
    *(uint4*)(AsB + (abyte ^ asw)) = p0;
    *(uint4*)(AsB + ((abyte + 16) ^ asw)) = p1;
    {
      const int n = tid >> 1, half = tid & 1;
      const u16* wsrc = Wt + (size_t)n * 384 + kc * 64 + half * 32;
      const uint4 w0 = *(const uint4*)(wsrc);
      const uint4 w1 = *(const uint4*)(wsrc + 8);
      const uint4 w2 = *(const uint4*)(wsrc + 16);
      const uint4 w3 = *(const uint4*)(wsrc + 24);
      const int bbyte = n * 128 + half * 64, bsw = (n & 7) << 4;
      *(uint4*)(BsB + ((bbyte) ^ bsw)) = w0;
      *(uint4*)(BsB + ((bbyte + 16) ^ bsw)) = w1;
      *(uint4*)(BsB + ((bbyte + 32) ^ bsw)) = w2;
      *(uint4*)(BsB + ((bbyte + 48) ^ bsw)) = w3;
    }
    __syncthreads();
    #pragma unroll
    for (int k2 = 0; k2 < 2; ++k2) {
      bf16x8 af[2], bfr[4];
      #pragma unroll
      for (int m = 0; m < 2; ++m) {
        const int row = wr * 32 + m * 16 + l15;
        af[m] = *(const bf16x8*)(AsB + ((row * 128 + k2 * 64 + lq * 16) ^ ((row & 7) << 4)));
      }
      #pragma unroll
      for (int n = 0; n < 4; ++n) {
        const int col = wc * 64 + n * 16 + l15;
        bfr[n] = *(const bf16x8*)(BsB + ((col * 128 + k2 * 64 + lq * 16) ^ ((col & 7) << 4)));
      }
      #pragma unroll
      for (int m = 0; m < 2; ++m)
        #pragma unroll
        for (int n = 0; n < 4; ++n)
          acc[m][n] = __builtin_amdgcn_mfma_f32_16x16x32_bf16(af[m], bfr[n], acc[m][n], 0, 0, 0);
    }
    __syncthreads();
  }

  float bb[4], s1[4], s2[4];
  #pragma unroll
  for (int n = 0; n < 4; ++n) { bb[n] = b[wc * 64 + n * 16 + l15]; s1[n] = 0.f; s2[n] = 0.f; }
  #pragma unroll
  for (int m = 0; m < 2; ++m)
    #pragma unroll
    for (int n = 0; n < 4; ++n) {
      const int col = wc * 64 + n * 16 + l15;
      #pragma unroll
      for (int r = 0; r < 4; ++r) {
        const int row = row0 + wr * 32 + m * 16 + lq * 4 + r;
        const float o = acc[m][n][r] + bb[n];
        s1[n] += o; s2[n] += o * o;
        h1[(size_t)row * L + col] = f2bf(o);
      }
    }
  #pragma unroll
  for (int n = 0; n < 4; ++n) {
    const int col = wc * 64 + n * 16 + l15;
    atomAddF(&red[col], s1[n]);
    atomAddF(&red[128 + col], s2[n]);
  }
  __syncthreads();
  const int slot = (bid & 63) * L;
  if (tid < 128) atomAddF(&gS[slot + tid], red[tid]);
  else atomAddF(&gS[64 * L + slot + (tid - 128)], red[tid]);
}

// ================= edge layer 2 (MFMA): ea += relu(relu(BN(h1)) @ W2 + b2) =================
__global__ __launch_bounds__(256) void k_edge_l2(
    const u16* __restrict__ h1, const float* __restrict__ ss,
    const u16* __restrict__ Wt, const float* __restrict__ b,
    float* __restrict__ ea)
{
  __shared__ u16 As[64 * 64];
  __shared__ u16 Bs[128 * 64];
  __shared__ float scs[128], shs[128];
  char* AsB = (char*)As; char* BsB = (char*)Bs;
  const int tid = threadIdx.x, bid = blockIdx.x, row0 = bid * 64;
  if (tid < 128) scs[tid] = ss[tid]; else shs[tid - 128] = ss[tid];
  const int ar = tid >> 2, as = tid & 3;
  const int lane = tid & 63, wid = tid >> 6;
  const int wr = wid >> 1, wc = wid & 1;
  const int l15 = lane & 15, lq = lane >> 4;
  f32x4 acc[2][4];
  #pragma unroll
  for (int m = 0; m < 2; ++m)
    #pragma unroll
    for (int n = 0; n < 4; ++n) acc[m][n] = (f32x4){0.f, 0.f, 0.f, 0.f};
  __syncthreads();

  for (int kc = 0; kc < 2; ++kc) {
    {
      const u16* hp = h1 + (size_t)(row0 + ar) * L + kc * 64 + as * 16;
      const uint4 r0 = *(const uint4*)hp;
      const uint4 r1 = *(const uint4*)(hp + 8);
      const int kg0 = kc * 64 + as * 16;
      const u32 uu0[4] = {r0.x, r0.y, r0.z, r0.w};
      const u32 uu1[4] = {r1.x, r1.y, r1.z, r1.w};
      uint4 p0, p1;
      u32 o0[4], o1[4];
      #pragma unroll
      for (int j = 0; j < 4; ++j) {
        int kg = kg0 + 2 * j;
        float a = fmaxf(bf2f(uu0[j] & 0xffffu) * scs[kg] + shs[kg], 0.f);
        float c = fmaxf(bf2f(uu0[j] >> 16) * scs[kg + 1] + shs[kg + 1], 0.f);
        o0[j] = pk2(a, c);
        kg = kg0 + 8 + 2 * j;
        a = fmaxf(bf2f(uu1[j] & 0xffffu) * scs[kg] + shs[kg], 0.f);
        c = fmaxf(bf2f(uu1[j] >> 16) * scs[kg + 1] + shs[kg + 1], 0.f);
        o1[j] = pk2(a, c);
      }
      p0.x = o0[0]; p0.y = o0[1]; p0.z = o0[2]; p0.w = o0[3];
      p1.x = o1[0]; p1.y = o1[1]; p1.z = o1[2]; p1.w = o1[3];
      const int abyte = ar * 128 + as * 32, asw = (ar & 7) << 4;
      *(uint4*)(AsB + (abyte ^ asw)) = p0;
      *(uint4*)(AsB + ((abyte + 16) ^ asw)) = p1;
    }
    {
      const int n = tid >> 1, half = tid & 1;
      const u16* wsrc = Wt + (size_t)n * 128 + kc * 64 + half * 32;
      const uint4 w0 = *(const uint4*)(wsrc);
      const uint4 w1 = *(const uint4*)(wsrc + 8);
      const uint4 w2 = *(const uint4*)(wsrc + 16);
      const uint4 w3 = *(const uint4*)(wsrc + 24);
      const int bbyte = n * 128 + half * 64, bsw = (n & 7) << 4;
      *(uint4*)(BsB + ((bbyte) ^ bsw)) = w0;
      *(uint4*)(BsB + ((bbyte + 16) ^ bsw)) = w1;
      *(uint4*)(BsB + ((bbyte + 32) ^ bsw)) = w2;
      *(uint4*)(BsB + ((bbyte + 48) ^ bsw)) = w3;
    }
    __syncthreads();
    #pragma unroll
    for (int k2 = 0; k2 < 2; ++k2) {
      bf16x8 af[2], bfr[4];
      #pragma unroll
      for (int m = 0; m < 2; ++m) {
        const int row = wr * 32 + m * 16 + l15;
        af[m] = *(const bf16x8*)(AsB + ((row * 128 + k2 * 64 + lq * 16) ^ ((row & 7) << 4)));
      }
      #pragma unroll
      for (int n = 0; n < 4; ++n) {
        const int col = wc * 64 + n * 16 + l15;
        bfr[n] = *(const bf16x8*)(BsB + ((col * 128 + k2 * 64 + lq * 16) ^ ((col & 7) << 4)));
      }
      #pragma unroll
      for (int m = 0; m < 2; ++m)
        #pragma unroll
        for (int n = 0; n < 4; ++n)
          acc[m][n] = __builtin_amdgcn_mfma_f32_16x16x32_bf16(af[m], bfr[n], acc[m][n], 0, 0, 0);
    }
    __syncthreads();
  }

  float bb[4];
  #pragma unroll
  for (int n = 0; n < 4; ++n) bb[n] = b[wc * 64 + n * 16 + l15];
  #pragma unroll
  for (int m = 0; m < 2; ++m)
    #pragma unroll
    for (int n = 0; n < 4; ++n) {
      const int col = wc * 64 + n * 16 + l15;
      #pragma unroll
      for (int r = 0; r < 4; ++r) {
        const int row = row0 + wr * 32 + m * 16 + lq * 4 + r;
        float* p = ea + (size_t)row * L + col;
        *p = fmaxf(acc[m][n][r] + bb[n], 0.f) + *p;
      }
    }
}

// ================= node layer 1 (MFMA): h1n = concat(x,agg) @ nW1 + nb1 ; BN stats =================
__global__ __launch_bounds__(256) void k_node_l1(
    const float* __restrict__ x, const float* __restrict__ agg,
    const u16* __restrict__ Wt, const float* __restrict__ b,
    u16* __restrict__ h1, float* __restrict__ gS)
{
  __shared__ u16 As[64 * 64];
  __shared__ u16 Bs[128 * 64];
  __shared__ float red[256];
  char* AsB = (char*)As; char* BsB = (char*)Bs;
  const int tid = threadIdx.x, bid = blockIdx.x, row0 = bid * 64;
  red[tid] = 0.f;
  const int ar = tid >> 2, as = tid & 3;
  const int rr = min(row0 + ar, NND - 1);
  const int lane = tid & 63, wid = tid >> 6;
  const int wr = wid >> 1, wc = wid & 1;
  const int l15 = lane & 15, lq = lane >> 4;
  f32x4 acc[2][4];
  #pragma unroll
  for (int m = 0; m < 2; ++m)
    #pragma unroll
    for (int n = 0; n < 4; ++n) acc[m][n] = (f32x4){0.f, 0.f, 0.f, 0.f};

  for (int kc = 0; kc < 4; ++kc) {
    const float* sp = (kc < 2) ? (x + (size_t)rr * L + kc * 64)
                               : (agg + (size_t)rr * L + (kc - 2) * 64);
    const float4 f0 = *(const float4*)(sp + as * 16);
    const float4 f1 = *(const float4*)(sp + as * 16 + 4);
    const float4 f2 = *(const float4*)(sp + as * 16 + 8);
    const float4 f3 = *(const float4*)(sp + as * 16 + 12);
    uint4 p0, p1;
    p0.x = pk2(f0.x, f0.y); p0.y = pk2(f0.z, f0.w);
    p0.z = pk2(f1.x, f1.y); p0.w = pk2(f1.z, f1.w);
    p1.x = pk2(f2.x, f2.y); p1.y = pk2(f2.z, f2.w);
    p1.z = pk2(f3.x, f3.y); p1.w = pk2(f3.z, f3.w);
    const int abyte = ar * 128 + as * 32, asw = (ar & 7) << 4;
    *(uint4*)(AsB + (abyte ^ asw)) = p0;
    *(uint4*)(AsB + ((abyte + 16) ^ asw)) = p1;
    {
      const int n = tid >> 1, half = tid & 1;
      const u16* wsrc = Wt + (size_t)n * 256 + kc * 64 + half * 32;
      const uint4 w0 = *(const uint4*)(wsrc);
      const uint4 w1 = *(const uint4*)(wsrc + 8);
      const uint4 w2 = *(const uint4*)(wsrc + 16);
      const uint4 w3 = *(const uint4*)(wsrc + 24);
      const int bbyte = n * 128 + half * 64, bsw = (n & 7) << 4;
      *(uint4*)(BsB + ((bbyte) ^ bsw)) = w0;
      *(uint4*)(BsB + ((bbyte + 16) ^ bsw)) = w1;
      *(uint4*)(BsB + ((bbyte + 32) ^ bsw)) = w2;
      *(uint4*)(BsB + ((bbyte + 48) ^ bsw)) = w3;
    }
    __syncthreads();
    #pragma unroll
    for (int k2 = 0; k2 < 2; ++k2) {
      bf16x8 af[2], bfr[4];
      #pragma unroll
      for (int m = 0; m < 2; ++m) {
        const int row = wr * 32 + m * 16 + l15;
        af[m] = *(const bf16x8*)(AsB + ((row * 128 + k2 * 64 + lq * 16) ^ ((row & 7) << 4)));
      }
      #pragma unroll
      for (int n = 0; n < 4; ++n) {
        const int col = wc * 64 + n * 16 + l15;
        bfr[n] = *(const bf16x8*)(BsB + ((col * 128 + k2 * 64 + lq * 16) ^ ((col & 7) << 4)));
      }
      #pragma unroll
      for (int m = 0; m < 2; ++m)
        #pragma unroll
        for (int n = 0; n < 4; ++n)
          acc[m][n] = __builtin_amdgcn_mfma_f32_16x16x32_bf16(af[m], bfr[n], acc[m][n], 0, 0, 0);
    }
    __syncthreads();
  }

  float bb[4], s1[4], s2[4];
  #pragma unroll
  for (int n = 0; n < 4; ++n) { bb[n] = b[wc * 64 + n * 16 + l15]; s1[n] = 0.f; s2[n] = 0.f; }
  #pragma unroll
  for (int m = 0; m < 2; ++m)
    #pragma unroll
    for (int n = 0; n < 4; ++n) {
      const int col = wc * 64 + n * 16 + l15;
      #pragma unroll
      for (int r = 0; r < 4; ++r) {
        const int row = row0 + wr * 32 + m * 16 + lq * 4 + r;
        if (row < NND) {
          const float o = acc[m][n][r] + bb[n];
          s1[n] += o; s2[n] += o * o;
          h1[(size_t)row * L + col] = f2bf(o);
        }
      }
    }
  #pragma unroll
  for (int n = 0; n < 4; ++n) {
    const int col = wc * 64 + n * 16 + l15;
    atomAddF(&red[col], s1[n]);
    atomAddF(&red[128 + col], s2[n]);
  }
  __syncthreads();
  const int slot = (bid & 63) * L;
  if (tid < 128) atomAddF(&gS[slot + tid], red[tid]);
  else atomAddF(&gS[64 * L + slot + (tid - 128)], red[tid]);
}

// ================= node layer 2 (MFMA): x += relu(relu(BN(h1n)) @ nW2 + nb2) =================
__global__ __launch_bounds__(256) void k_node_l2(
    const u16* __restrict__ h1, const float* __restrict__ ss,
    const u16* __restrict__ Wt, const float* __restrict__ b,
    float* __restrict__ x)
{
  __shared__ u16 As[64 * 64];
  __shared__ u16 Bs[128 * 64];
  __shared__ float scs[128], shs[128];
  char* AsB = (char*)As; char* BsB = (char*)Bs;
  const int tid = threadIdx.x, bid = blockIdx.x, row0 = bid * 64;
  if (tid < 128) scs[tid] = ss[tid]; else shs[tid - 128] = ss[tid];
  const int ar = tid >> 2, as = tid & 3;
  const int rr = min(row0 + ar, NND - 1);
  const int lane = tid & 63, wid = tid >> 6;
  const int wr = wid >> 1, wc = wid & 1;
  const int l15 = lane & 15, lq = lane >> 4;
  f32x4 acc[2][4];
  #pragma unroll
  for (int m = 0; m < 2; ++m)
    #pragma unroll
    for (int n = 0; n < 4; ++n) acc[m][n] = (f32x4){0.f, 0.f, 0.f, 0.f};
  __syncthreads();

  for (int kc = 0; kc < 2; ++kc) {
    {
      const u16* hp = h1 + (size_t)rr * L + kc * 64 + as * 16;
      const uint4 r0 = *(const uint4*)hp;
      const uint4 r1 = *(const uint4*)(hp + 8);
      const int kg0 = kc * 64 + as * 16;
      const u32 uu0[4] = {r0.x, r0.y, r0.z, r0.w};
      const u32 uu1[4] = {r1.x, r1.y, r1.z, r1.w};
      uint4 p0, p1;
      u32 o0[4], o1[4];
      #pragma unroll
      for (int j = 0; j < 4; ++j) {
        int kg = kg0 + 2 * j;
        float a = fmaxf(bf2f(uu0[j] & 0xffffu) * scs[kg] + shs[kg], 0.f);
        float c = fmaxf(bf2f(uu0[j] >> 16) * scs[kg + 1] + shs[kg + 1], 0.f);
        o0[j] = pk2(a, c);
        kg = kg0 + 8 + 2 * j;
        a = fmaxf(bf2f(uu1[j] & 0xffffu) * scs[kg] + shs[kg], 0.f);
        c = fmaxf(bf2f(uu1[j] >> 16) * scs[kg + 1] + shs[kg + 1], 0.f);
        o1[j] = pk2(a, c);
      }
      p0.x = o0[0]; p0.y = o0[1]; p0.z = o0[2]; p0.w = o0[3];
      p1.x = o1[0]; p1.y = o1[1]; p1.z = o1[2]; p1.w = o1[3];
      const int abyte = ar * 128 + as * 32, asw = (ar & 7) << 4;
      *(uint4*)(AsB + (abyte ^ asw)) = p0;
      *(uint4*)(AsB + ((abyte + 16) ^ asw)) = p1;
    }
    {
      const int n = tid >> 1, half = tid & 1;
      const u16* wsrc = Wt + (size_t)n * 128 + kc * 64 + half * 32;
      const uint4 w0 = *(const uint4*)(wsrc);
      const uint4 w1 = *(const uint4*)(wsrc + 8);
      const uint4 w2 = *(const uint4*)(wsrc + 16);
      const uint4 w3 = *(const uint4*)(wsrc + 24);
      const int bbyte = n * 128 + half * 64, bsw = (n & 7) << 4;
      *(uint4*)(BsB + ((bbyte) ^ bsw)) = w0;
      *(uint4*)(BsB + ((bbyte + 16) ^ bsw)) = w1;
      *(uint4*)(BsB + ((bbyte + 32) ^ bsw)) = w2;
      *(uint4*)(BsB + ((bbyte + 48) ^ bsw)) = w3;
    }
    __syncthreads();
    #pragma unroll
    for (int k2 = 0; k2 < 2; ++k2) {
      bf16x8 af[2], bfr[4];
      #pragma unroll
      for (int m = 0; m < 2; ++m) {
        const int row = wr * 32 + m * 16 + l15;
        af[m] = *(const bf16x8*)(AsB + ((row * 128 + k2 * 64 + lq * 16) ^ ((row & 7) << 4)));
      }
      #pragma unroll
      for (int n = 0; n < 4; ++n) {
        const int col = wc * 64 + n * 16 + l15;
        bfr[n] = *(const bf16x8*)(BsB + ((col * 128 + k2 * 64 + lq * 16) ^ ((col & 7) << 4)));
      }
      #pragma unroll
      for (int m = 0; m < 2; ++m)
        #pragma unroll
        for (int n = 0; n < 4; ++n)
          acc[m][n] = __builtin_amdgcn_mfma_f32_16x16x32_bf16(af[m], bfr[n], acc[m][n], 0, 0, 0);
    }
    __syncthreads();
  }

  float bb[4];
  #pragma unroll
  for (int n = 0; n < 4; ++n) bb[n] = b[wc * 64 + n * 16 + l15];
  #pragma unroll
  for (int m = 0; m < 2; ++m)
    #pragma unroll
    for (int n = 0; n < 4; ++n) {
      const int col = wc * 64 + n * 16 + l15;
      #pragma unroll
      for (int r = 0; r < 4; ++r) {
        const int row = row0 + wr * 32 + m * 16 + lq * 4 + r;
        if (row < NND) {
          float* p = x + (size_t)row * L + col;
          *p = fmaxf(acc[m][n][r] + bb[n], 0.f) + *p;
        }
      }
    }
}

extern "C" void kernel_launch(void* const* d_in, const int* in_sizes, int n_in,
                              void* d_out, int out_size, void* d_ws, size_t ws_size,
                              hipStream_t stream) {
  (void)in_sizes; (void)n_in; (void)out_size; (void)ws_size;
  const float* in_x  = (const float*)d_in[0];
  const float* in_ea = (const float*)d_in[1];
  const int*   ei    = (const int*)d_in[2];
  const float* eW1 = (const float*)d_in[3];
  const float* eb1 = (const float*)d_in[4];
  const float* eg1 = (const float*)d_in[5];
  const float* ebe1= (const float*)d_in[6];
  const float* eW2 = (const float*)d_in[7];
  const float* eb2 = (const float*)d_in[8];
  const float* nW1 = (const float*)d_in[9];
  const float* nb1 = (const float*)d_in[10];
  const float* ng1 = (const float*)d_in[11];
  const float* nbe1= (const float*)d_in[12];
  const float* nW2 = (const float*)d_in[13];
  const float* nb2 = (const float*)d_in[14];

  float* x  = (float*)d_out;                    // [NND][L]
  float* ea = (float*)d_out + (size_t)NND * L;  // [E_N][L]

  char* w = (char*)d_ws;
  u16* h1e  = (u16*)w;   w += (size_t)E_N * L * sizeof(u16);
  u16* h1n  = (u16*)w;   w += (size_t)NND * L * sizeof(u16);
  float* agg = (float*)w; w += (size_t)NND * L * sizeof(float);
  float* gS  = (float*)w; w += (size_t)2 * 64 * L * sizeof(float);
  float* ss  = (float*)w; w += 4096;
  u16* eW1t = (u16*)w;   w += (size_t)4 * 128 * 384 * sizeof(u16);
  u16* eW2t = (u16*)w;   w += (size_t)4 * 128 * 128 * sizeof(u16);
  u16* nW1t = (u16*)w;   w += (size_t)4 * 128 * 256 * sizeof(u16);
  u16* nW2t = (u16*)w;   w += (size_t)4 * 128 * 128 * sizeof(u16);
  int* cnt    = (int*)w; w += (size_t)NND * sizeof(int);
  int* cur    = (int*)w; w += (size_t)NND * sizeof(int);
  int* startA = (int*)w; w += (size_t)(NND + 1) * sizeof(int);
  int* eids   = (int*)w; w += (size_t)E_N * sizeof(int);

  const int* srcI = ei;        // edge_index[0]
  const int* dstI = ei + E_N;  // edge_index[1]

  // ---- per-launch pre-pass: weight transpose + CSR build ----
  k_wt<<<(4 * 384 * 128 + 255) / 256, 256, 0, stream>>>(eW1, eW1t, 384);
  k_wt<<<(4 * 128 * 128 + 255) / 256, 256, 0, stream>>>(eW2, eW2t, 128);
  k_wt<<<(4 * 256 * 128 + 255) / 256, 256, 0, stream>>>(nW1, nW1t, 256);
  k_wt<<<(4 * 128 * 128 + 255) / 256, 256, 0, stream>>>(nW2, nW2t, 128);
  hipMemsetAsync(cnt, 0, (size_t)NND * sizeof(int), stream);
  hipMemsetAsync(cur, 0, (size_t)NND * sizeof(int), stream);
  k_hist<<<(E_N + 255) / 256, 256, 0, stream>>>(dstI, cnt);
  k_scan<<<1, 1024, 0, stream>>>(cnt, startA);
  k_fill<<<(E_N + 255) / 256, 256, 0, stream>>>(dstI, startA, cur, eids);

  hipMemcpyAsync(x, in_x, (size_t)NND * L * sizeof(float), hipMemcpyDeviceToDevice, stream);
  hipMemcpyAsync(ea, in_ea, (size_t)E_N * L * sizeof(float), hipMemcpyDeviceToDevice, stream);

  const int egrid = E_N / 64;            // 9375
  const int ngrid = (NND + 63) / 64;     // 782

  for (int s = 0; s < 4; ++s) {
    hipMemsetAsync(gS, 0, (size_t)2 * 64 * L * sizeof(float), stream);
    k_edge_l1<<<egrid, 256, 0, stream>>>(x, ea, srcI, dstI,
        eW1t + (size_t)s * 128 * 384, eb1 + (size_t)s * L, h1e, gS);
    k_bnfin<<<1, 128, 0, stream>>>(gS, eg1 + (size_t)s * L, ebe1 + (size_t)s * L,
        1.f / (float)E_N, ss);
    k_edge_l2<<<egrid, 256, 0, stream>>>(h1e, ss,
        eW2t + (size_t)s * 128 * 128, eb2 + (size_t)s * L, ea);
    k_agg<<<(NND + 3) / 4, 256, 0, stream>>>(ea, startA, eids, agg);
    hipMemsetAsync(gS, 0, (size_t)2 * 64 * L * sizeof(float), stream);
    k_node_l1<<<ngrid, 256, 0, stream>>>(x, agg,
        nW1t + (size_t)s * 128 * 256, nb1 + (size_t)s * L, h1n, gS);
    k_bnfin<<<1, 128, 0, stream>>>(gS, ng1 + (size_t)s * L, nbe1 + (size_t)s * L,
        1.f / (float)NND, ss);
    k_node_l2<<<ngrid, 256, 0, stream>>>(h1n, ss,
        nW2t + (size_t)s * 128 * 128, nb2 + (size_t)s * L, x);
  }
}